// Round 9
// baseline (481.996 us; speedup 1.0000x reference)
//
#include <hip/hip_runtime.h>

typedef unsigned short u16;
typedef __attribute__((ext_vector_type(8))) short short8;
typedef __attribute__((ext_vector_type(4))) float floatx4;

__device__ __forceinline__ float b2f(unsigned int ubits) {
  union { unsigned int i; float f; } cv; cv.i = ubits << 16; return cv.f;
}
__device__ __forceinline__ float hi2f(unsigned int u) {
  union { unsigned int i; float f; } cv; cv.i = u & 0xffff0000u; return cv.f;
}
__device__ __forceinline__ float lo2f(unsigned int u) {
  union { unsigned int i; float f; } cv; cv.i = u << 16; return cv.f;
}
__device__ __forceinline__ u16 f2b(float f) {
  unsigned int u = __builtin_bit_cast(unsigned int, f);
  u += 0x7fffu + ((u >> 16) & 1u);   // RNE
  return (u16)(u >> 16);
}
__device__ __forceinline__ float lrelu(float v) { return v > 0.f ? v : 0.2f * v; }
__device__ __forceinline__ float rdf(bool isbf, const void* p, int idx) {
  return isbf ? b2f((unsigned int)((const u16*)p)[idx]) : ((const float*)p)[idx];
}

// ---------------- init: zero deg + dtype detect (block 0) ----------------
__global__ __launch_bounds__(256) void init_kernel(int* __restrict__ deg, int n,
                                                   const u16* __restrict__ probe,
                                                   int* __restrict__ flag) {
  int i0 = (blockIdx.x * 256 + threadIdx.x) * 4;
  if (i0 + 3 < n) {
    *(int4*)(deg + i0) = make_int4(0, 0, 0, 0);
  } else {
    for (int j = 0; j < 4; j++) if (i0 + j < n) deg[i0 + j] = 0;
  }
  if (blockIdx.x == 0 && threadIdx.x < 64) {
    int lane = threadIdx.x;
    int cnt = 0;
    for (int i = lane; i < 256; i += 64) {
      unsigned int u = probe[i];
      unsigned int e = (u >> 7) & 0xFFu;
      if ((u & 0x7fffu) == 0 || (e >= 60 && e <= 191)) cnt++;
    }
#pragma unroll
    for (int off = 32; off; off >>= 1) cnt += __shfl_down(cnt, off, 64);
    if (lane == 0) *flag = (cnt >= 240) ? 1 : 0;
  }
}

// ---------------- CSR build ----------------
__global__ __launch_bounds__(256) void hist_kernel(const int* __restrict__ dst, int E,
                                                   int* __restrict__ deg) {
  int i = blockIdx.x * 256 + threadIdx.x;
  if (i < E) atomicAdd(deg + dst[i], 1);
}

#define SCB 1024  // nodes per scan block (256 thr x 4)

__global__ __launch_bounds__(256) void scan_phaseA(const int* __restrict__ deg,
                                                   int* __restrict__ bsum, int n) {
  int i0 = blockIdx.x * SCB + threadIdx.x * 4;
  int s = 0;
  if (i0 + 3 < n) {
    int4 v = *(const int4*)(deg + i0);
    s = v.x + v.y + v.z + v.w;
  } else {
    for (int j = 0; j < 4; j++) if (i0 + j < n) s += deg[i0 + j];
  }
#pragma unroll
  for (int off = 32; off; off >>= 1) s += __shfl_down(s, off, 64);
  __shared__ int ws4[4];
  int lane = threadIdx.x & 63, wid = threadIdx.x >> 6;
  if (lane == 0) ws4[wid] = s;
  __syncthreads();
  if (threadIdx.x == 0) bsum[blockIdx.x] = ws4[0] + ws4[1] + ws4[2] + ws4[3];
}

__global__ void scan_phaseB(const int* __restrict__ bsum, int* __restrict__ boff,
                            int PB, int* __restrict__ rowptr, int n) {
  int lane = threadIdx.x;  // 64, PB <= 64
  int v = (lane < PB) ? bsum[lane] : 0;
  int incl = v;
#pragma unroll
  for (int off = 1; off < 64; off <<= 1) {
    int t = __shfl_up(incl, off, 64);
    if (lane >= off) incl += t;
  }
  if (lane < PB) boff[lane] = incl - v;
  if (lane == 63) rowptr[n] = incl;
}

__global__ __launch_bounds__(256) void scan_phaseC(const int* __restrict__ deg,
                                                   const int* __restrict__ boff,
                                                   int* __restrict__ rowptr,
                                                   int* __restrict__ cursor, int n) {
  int i0 = blockIdx.x * SCB + threadIdx.x * 4;
  int v0 = 0, v1 = 0, v2 = 0, v3 = 0;
  if (i0 + 3 < n) {
    int4 v = *(const int4*)(deg + i0);
    v0 = v.x; v1 = v.y; v2 = v.z; v3 = v.w;
  } else {
    if (i0 < n) v0 = deg[i0];
    if (i0 + 1 < n) v1 = deg[i0 + 1];
    if (i0 + 2 < n) v2 = deg[i0 + 2];
    if (i0 + 3 < n) v3 = deg[i0 + 3];
  }
  int local = v0 + v1 + v2 + v3;
  int lane = threadIdx.x & 63, wid = threadIdx.x >> 6;
  int incl = local;
#pragma unroll
  for (int off = 1; off < 64; off <<= 1) {
    int t = __shfl_up(incl, off, 64);
    if (lane >= off) incl += t;
  }
  __shared__ int ws4[4];
  if (lane == 63) ws4[wid] = incl;
  __syncthreads();
  int woff = 0;
  for (int w = 0; w < wid; w++) woff += ws4[w];
  int run = boff[blockIdx.x] + woff + incl - local;
  if (i0 < n)     { rowptr[i0] = run;     cursor[i0] = run; }     run += v0;
  if (i0 + 1 < n) { rowptr[i0 + 1] = run; cursor[i0 + 1] = run; } run += v1;
  if (i0 + 2 < n) { rowptr[i0 + 2] = run; cursor[i0 + 2] = run; } run += v2;
  if (i0 + 3 < n) { rowptr[i0 + 3] = run; cursor[i0 + 3] = run; }
}

__global__ __launch_bounds__(256) void fill_kernel(const int* __restrict__ src,
                                                   const int* __restrict__ dst, int E,
                                                   int* __restrict__ cursor,
                                                   int* __restrict__ colarr) {
  int i = blockIdx.x * 256 + threadIdx.x;
  if (i < E) {
    int p = atomicAdd(cursor + dst[i], 1);
    colarr[p] = src[i];
  }
}

// -------- all weight transposes in one kernel: W[K][N] (native) -> Wt[Npad][K] bf16 --------
struct TWDesc {
  const void* W[5];
  int K[5];
  int Nc[5];
  int base[6];  // u16 offsets
};

__global__ __launch_bounds__(256) void transpose_all(TWDesc d, u16* __restrict__ out,
                                                     const int* __restrict__ flagp) {
  bool isbf = (*flagp != 0);
  int idx = blockIdx.x * 256 + threadIdx.x;
  if (idx >= d.base[5]) return;
  int s = 0;
  while (idx >= d.base[s + 1]) s++;
  int local = idx - d.base[s];
  int K = d.K[s], Nc = d.Nc[s];
  int nn = local / K;
  int k = local - nn * K;
  out[idx] = (nn < Nc) ? f2b(rdf(isbf, d.W[s], k * Nc + nn)) : (u16)0;
}

// ---------------- A-fragment load (runtime dtype, exact-zero -> me) ----------------
__device__ __forceinline__ short8 load_a_me(const void* Av, int lda, const void* me,
                                            int r, int k0, int q, bool isbf) {
  short8 a;
  if (isbf) {
    a = *(const short8*)((const u16*)Av + (long)r * lda + k0 + q * 8);
#pragma unroll
    for (int j = 0; j < 8; j++) {
      if (((u16)a[j] & 0x7fffu) == 0)
        a[j] = (short)((const u16*)me)[k0 + q * 8 + j];
    }
  } else {
    const float* A = (const float*)Av;
    const uint4* p = (const uint4*)(A + (long)r * lda + k0 + q * 8);
    uint4 w0 = p[0];
    uint4 w1 = p[1];
    unsigned int ww[8] = {w0.x, w0.y, w0.z, w0.w, w1.x, w1.y, w1.z, w1.w};
#pragma unroll
    for (int j = 0; j < 8; j++) {
      if ((ww[j] & 0x7fffffffu) == 0)
        a[j] = (short)f2b(((const float*)me)[k0 + q * 8 + j]);
      else
        a[j] = (short)((ww[j] + 0x8000u) >> 16);  // cheap round-half-up
    }
  }
  return a;
}

// ------------- fused layer-1 GEMM: tbuf[r] = [ x'@W1e | c'@W1c ]  (64 rows/block) -------------
__global__ __launch_bounds__(256) void gemm_l1(
    const void* __restrict__ x, const void* __restrict__ cc,
    const void* __restrict__ mex, const void* __restrict__ mec,
    const u16* __restrict__ w1e_t, const u16* __restrict__ w1c_t,
    int M, u16* __restrict__ tb, const int* __restrict__ flagp) {
  bool isbf = (*flagp != 0);
  int wid = threadIdx.x >> 6;
  int lane = threadIdx.x & 63;
  int l15 = lane & 15;
  int q = lane >> 4;
  int row0 = blockIdx.x * 64 + wid * 16;
  int r = row0 + l15;
  if (r >= M) r = M - 1;

  floatx4 acce[8], accc[8];
#pragma unroll
  for (int n = 0; n < 8; n++) { acce[n] = (floatx4){0,0,0,0}; accc[n] = (floatx4){0,0,0,0}; }

  for (int k0 = 0; k0 < 256; k0 += 32) {
    short8 a = load_a_me(x, 256, mex, r, k0, q, isbf);
#pragma unroll
    for (int n = 0; n < 8; n++) {
      short8 b = *(const short8*)(w1e_t + (n * 16 + l15) * 256 + k0 + q * 8);
      acce[n] = __builtin_amdgcn_mfma_f32_16x16x32_bf16(a, b, acce[n], 0, 0, 0);
    }
  }
  for (int k0 = 0; k0 < 128; k0 += 32) {
    short8 a = load_a_me(cc, 128, mec, r, k0, q, isbf);
#pragma unroll
    for (int n = 0; n < 8; n++) {
      short8 b = *(const short8*)(w1c_t + (n * 16 + l15) * 128 + k0 + q * 8);
      accc[n] = __builtin_amdgcn_mfma_f32_16x16x32_bf16(a, b, accc[n], 0, 0, 0);
    }
  }
#pragma unroll
  for (int n = 0; n < 8; n++)
#pragma unroll
    for (int rr = 0; rr < 4; rr++) {
      int row = row0 + q * 4 + rr;
      if (row < M) {
        tb[(long)row * 256 + n * 16 + l15] = f2b(acce[n][rr]);
        tb[(long)row * 256 + 128 + n * 16 + l15] = f2b(accc[n][rr]);
      }
    }
}

// ------------- fused layer-2 GEMM: tbuf[r] = [ u_e@W2e | u_c@W2c ]  (A = ubuf bf16) -------------
__global__ __launch_bounds__(256) void gemm_l2(
    const u16* __restrict__ u,
    const u16* __restrict__ w2e_t, const u16* __restrict__ w2c_t,
    int M, u16* __restrict__ tb) {
  int wid = threadIdx.x >> 6;
  int lane = threadIdx.x & 63;
  int l15 = lane & 15;
  int q = lane >> 4;
  int row0 = blockIdx.x * 64 + wid * 16;
  int r = row0 + l15;
  if (r >= M) r = M - 1;

  floatx4 acce[8], accc[8];
#pragma unroll
  for (int n = 0; n < 8; n++) { acce[n] = (floatx4){0,0,0,0}; accc[n] = (floatx4){0,0,0,0}; }

  for (int k0 = 0; k0 < 128; k0 += 32) {
    short8 ae = *(const short8*)(u + (long)r * 256 + k0 + q * 8);
    short8 ac = *(const short8*)(u + (long)r * 256 + 128 + k0 + q * 8);
#pragma unroll
    for (int n = 0; n < 8; n++) {
      short8 be = *(const short8*)(w2e_t + (n * 16 + l15) * 128 + k0 + q * 8);
      short8 bc = *(const short8*)(w2c_t + (n * 16 + l15) * 128 + k0 + q * 8);
      acce[n] = __builtin_amdgcn_mfma_f32_16x16x32_bf16(ae, be, acce[n], 0, 0, 0);
      accc[n] = __builtin_amdgcn_mfma_f32_16x16x32_bf16(ac, bc, accc[n], 0, 0, 0);
    }
  }
#pragma unroll
  for (int n = 0; n < 8; n++)
#pragma unroll
    for (int rr = 0; rr < 4; rr++) {
      int row = row0 + q * 4 + rr;
      if (row < M) {
        tb[(long)row * 256 + n * 16 + l15] = f2b(acce[n][rr]);
        tb[(long)row * 256 + 128 + n * 16 + l15] = f2b(accc[n][rr]);
      }
    }
}

// 8-edge-unrolled half-row gather: per lane 2 feats (4B uint) at t[src*256 + f]
#define GATHER8H                                                        \
  for (; e + 8 <= e1; e += 8) {                                         \
    int c0 = colarr[e], c1 = colarr[e + 1], c2 = colarr[e + 2], c3 = colarr[e + 3]; \
    int c4 = colarr[e + 4], c5 = colarr[e + 5], c6 = colarr[e + 6], c7 = colarr[e + 7]; \
    unsigned p0 = *(const unsigned*)(tb + ((long)c0 << 8));             \
    unsigned p1 = *(const unsigned*)(tb + ((long)c1 << 8));             \
    unsigned p2 = *(const unsigned*)(tb + ((long)c2 << 8));             \
    unsigned p3 = *(const unsigned*)(tb + ((long)c3 << 8));             \
    unsigned p4 = *(const unsigned*)(tb + ((long)c4 << 8));             \
    unsigned p5 = *(const unsigned*)(tb + ((long)c5 << 8));             \
    unsigned p6 = *(const unsigned*)(tb + ((long)c6 << 8));             \
    unsigned p7 = *(const unsigned*)(tb + ((long)c7 << 8));             \
    a0 += lo2f(p0); a1 += hi2f(p0); a0 += lo2f(p1); a1 += hi2f(p1);     \
    a0 += lo2f(p2); a1 += hi2f(p2); a0 += lo2f(p3); a1 += hi2f(p3);     \
    a0 += lo2f(p4); a1 += hi2f(p4); a0 += lo2f(p5); a1 += hi2f(p5);     \
    a0 += lo2f(p6); a1 += hi2f(p6); a0 += lo2f(p7); a1 += hi2f(p7);     \
  }                                                                     \
  for (; e < e1; e++) {                                                 \
    int c = colarr[e];                                                  \
    unsigned p = *(const unsigned*)(tb + ((long)c << 8));               \
    a0 += lo2f(p); a1 += hi2f(p);                                       \
  }

// ------- agg layer-1, XCD-half-split: block's xcd slot (blockIdx&7) picks feature half.
// Persistent grid 8*GS blocks; wave per node-half; 2 feats/lane. u out bf16. -------
__global__ __launch_bounds__(256) void agg1_half(
    const u16* __restrict__ t, const int* __restrict__ rowptr, const int* __restrict__ colarr,
    const void* __restrict__ epsE, const void* __restrict__ epsC,
    const void* __restrict__ bE, const void* __restrict__ bC,
    u16* __restrict__ u, int N, int ngroups, const int* __restrict__ flagp) {
  bool isbf = (*flagp != 0);
  int b = blockIdx.x;
  int h = (b >> 2) & 1;    // xcd = b&7; half = xcd>>2
  int quad = b & 3;        // which 4-node slice of the 16-node group
  int wid = threadIdx.x >> 6, lane = threadIdx.x & 63;
  int f = h * 128 + lane * 2;
  const u16* tb = t + f;
  float eps2 = 2.0f + rdf(isbf, h ? epsC : epsE, 0);
  const void* bp = h ? bC : bE;
  int bi = h ? (f - 128) : f;
  float bb0 = rdf(isbf, bp, bi);
  float bb1 = rdf(isbf, bp, bi + 1);
  int gstride = gridDim.x >> 3;
  for (int g = b >> 3; g < ngroups; g += gstride) {
    int node = g * 16 + quad * 4 + wid;
    if (node >= N) continue;
    float a0 = 0.f, a1 = 0.f;
    int e = rowptr[node], e1 = rowptr[node + 1];
    GATHER8H
    unsigned ps = *(const unsigned*)(tb + ((long)node << 8));
    a0 = lrelu(a0 + eps2 * lo2f(ps) + bb0);
    a1 = lrelu(a1 + eps2 * hi2f(ps) + bb1);
    *(unsigned*)(u + ((long)node << 8) + f) = ((unsigned)f2b(a1) << 16) | f2b(a0);
  }
}

// ------- agg layer-2 + head, XCD-half-split: partial head sums atomicAdd'ed into out -------
__global__ __launch_bounds__(256) void agg2_half(
    const u16* __restrict__ t, const int* __restrict__ rowptr, const int* __restrict__ colarr,
    const void* __restrict__ epsE, const void* __restrict__ epsC,
    const void* __restrict__ bE, const void* __restrict__ bC,
    const u16* __restrict__ wm_t, float* __restrict__ out,
    int N, int ngroups, const int* __restrict__ flagp) {
  bool isbf = (*flagp != 0);
  int b = blockIdx.x;
  int h = (b >> 2) & 1;
  int quad = b & 3;
  int wid = threadIdx.x >> 6, lane = threadIdx.x & 63;
  int f = h * 128 + lane * 2;
  const u16* tb = t + f;
  float eps2 = 2.0f + rdf(isbf, h ? epsC : epsE, 0);
  const void* bp = h ? bC : bE;
  int bi = h ? (f - 128) : f;
  float bb0 = rdf(isbf, bp, bi);
  float bb1 = rdf(isbf, bp, bi + 1);
  float2 wf[8];
#pragma unroll
  for (int cc = 0; cc < 8; cc++) {
    unsigned w = *(const unsigned*)(wm_t + cc * 256 + f);
    wf[cc] = make_float2(lo2f(w), hi2f(w));
  }
  int gstride = gridDim.x >> 3;
  for (int g = b >> 3; g < ngroups; g += gstride) {
    int node = g * 16 + quad * 4 + wid;
    if (node >= N) continue;
    float a0 = 0.f, a1 = 0.f;
    int e = rowptr[node], e1 = rowptr[node + 1];
    GATHER8H
    unsigned ps = *(const unsigned*)(tb + ((long)node << 8));
    a0 = lrelu(a0 + eps2 * lo2f(ps) + bb0);
    a1 = lrelu(a1 + eps2 * hi2f(ps) + bb1);
    float p[8];
#pragma unroll
    for (int cc = 0; cc < 8; cc++) p[cc] = a0 * wf[cc].x + a1 * wf[cc].y;
    // value-splitting reduction: bit5 8->4 cols, bit4 4->2, bit3 2->1, butterfly 4,2,1
    float q[4];
#pragma unroll
    for (int cc = 0; cc < 4; cc++) {
      float send = (lane & 32) ? p[cc] : p[cc + 4];
      float recv = __shfl_xor(send, 32, 64);
      q[cc] = ((lane & 32) ? p[cc + 4] : p[cc]) + recv;
    }
    float r2[2];
#pragma unroll
    for (int cc = 0; cc < 2; cc++) {
      float send = (lane & 16) ? q[cc] : q[cc + 2];
      float recv = __shfl_xor(send, 16, 64);
      r2[cc] = ((lane & 16) ? q[cc + 2] : q[cc]) + recv;
    }
    float send = (lane & 8) ? r2[0] : r2[1];
    float recv = __shfl_xor(send, 8, 64);
    float s = ((lane & 8) ? r2[1] : r2[0]) + recv;
    s += __shfl_xor(s, 4, 64);
    s += __shfl_xor(s, 2, 64);
    s += __shfl_xor(s, 1, 64);
    if ((lane & 7) == 0)
      atomicAdd(out + (long)node * 8 + ((lane >> 3) & 7), s);
  }
}

// ------- head epilogue: out = lrelu(out + bm) -------
__global__ __launch_bounds__(256) void head_epi(float* __restrict__ out, const void* __restrict__ bm,
                                                int total, const int* __restrict__ flagp) {
  bool isbf = (*flagp != 0);
  int i = blockIdx.x * 256 + threadIdx.x;
  if (i < total) out[i] = lrelu(out[i] + rdf(isbf, bm, i & 7));
}

// ---------------- central-node MLP (f32 in, f32 out) ----------------
__global__ __launch_bounds__(128) void mlp_kernel(
    const float* __restrict__ outbuf, const int* __restrict__ central,
    const void* __restrict__ Wp1, const void* __restrict__ bp1,
    const void* __restrict__ Wp2, const void* __restrict__ bp2,
    float* __restrict__ logits, const int* __restrict__ flagp) {
  __shared__ float h1[128];
  __shared__ float o[8];
  bool isbf = (*flagp != 0);
  int b = blockIdx.x, tid = threadIdx.x;
  int node = central[b];
  if (tid < 8) o[tid] = outbuf[node * 8 + tid];
  __syncthreads();
  float s = rdf(isbf, bp1, tid);
#pragma unroll
  for (int k = 0; k < 8; k++) s += o[k] * rdf(isbf, Wp1, k * 128 + tid);
  h1[tid] = fmaxf(s, 0.f);
  __syncthreads();
  if (tid < 8) {
    float s2 = rdf(isbf, bp2, tid);
    for (int k = 0; k < 128; k++) s2 += h1[k] * rdf(isbf, Wp2, k * 8 + tid);
    logits[b * 8 + tid] = s2;
  }
}

extern "C" void kernel_launch(void* const* d_in, const int* in_sizes, int n_in,
                              void* d_out, int out_size, void* d_ws, size_t ws_size,
                              hipStream_t stream) {
  const void* x    = d_in[0];
  const void* c    = d_in[1];
  const int* eidx  = (const int*)d_in[2];
  const int* cidx  = (const int*)d_in[3];
  const void* me_x = d_in[4];
  const void* me_c = d_in[5];
  const void* W1e  = d_in[6];
  const void* b1e  = d_in[7];
  const void* e1e  = d_in[8];
  const void* W2e  = d_in[9];
  const void* b2e  = d_in[10];
  const void* e2e  = d_in[11];
  const void* W1c  = d_in[12];
  const void* b1c  = d_in[13];
  const void* e1c  = d_in[14];
  const void* W2c  = d_in[15];
  const void* b2c  = d_in[16];
  const void* e2c  = d_in[17];
  const void* Wm   = d_in[18];
  const void* bm   = d_in[19];
  const void* Wp1  = d_in[20];
  const void* bp1  = d_in[21];
  const void* Wp2  = d_in[22];
  const void* bp2  = d_in[23];

  const int N = in_sizes[0] / 256;   // 50000
  const int E = in_sizes[2] / 2;     // 800000
  const int Cn = in_sizes[3];        // 512
  const int* src = eidx;
  const int* dst = eidx + E;

  char* ws = (char*)d_ws;
  int* deg    = (int*)(ws + 0);
  int* rowptr = (int*)(ws + 200192);
  int* cursor = (int*)(ws + 400384);
  int* colarr = (int*)(ws + 600576);
  u16* tbuf   = (u16*)(ws + 3800576);
  u16* ubuf   = (u16*)(ws + 29400576);
  u16* wt_all = (u16*)(ws + 55000576);
  int* flag   = (int*)(ws + 55172608);
  int* bsum   = (int*)(ws + 55172864);
  int* boff   = (int*)(ws + 55173120);

  u16* w1e_t = wt_all + 0;       // [128][256]
  u16* w1c_t = wt_all + 32768;   // [128][128]
  u16* w2e_t = wt_all + 49152;   // [128][128]
  u16* w2c_t = wt_all + 65536;   // [128][128]
  u16* wm_t  = wt_all + 81920;   // [16][256]

  // zero the out region early (atomic head partials accumulate into it)
  hipMemsetAsync(d_out, 0, (size_t)N * 8 * sizeof(float), stream);

  init_kernel<<<(N + 1023) / 1024, 256, 0, stream>>>(deg, N, (const u16*)x, flag);

  hist_kernel<<<(E + 255) / 256, 256, 0, stream>>>(dst, E, deg);
  int PB = (N + SCB - 1) / SCB;  // 49
  scan_phaseA<<<PB, 256, 0, stream>>>(deg, bsum, N);
  scan_phaseB<<<1, 64, 0, stream>>>(bsum, boff, PB, rowptr, N);
  scan_phaseC<<<PB, 256, 0, stream>>>(deg, boff, rowptr, cursor, N);
  fill_kernel<<<(E + 255) / 256, 256, 0, stream>>>(src, dst, E, cursor, colarr);

  TWDesc td;
  td.W[0] = W1e; td.K[0] = 256; td.Nc[0] = 128;
  td.W[1] = W1c; td.K[1] = 128; td.Nc[1] = 128;
  td.W[2] = W2e; td.K[2] = 128; td.Nc[2] = 128;
  td.W[3] = W2c; td.K[3] = 128; td.Nc[3] = 128;
  td.W[4] = Wm;  td.K[4] = 256; td.Nc[4] = 8;
  td.base[0] = 0; td.base[1] = 32768; td.base[2] = 49152;
  td.base[3] = 65536; td.base[4] = 81920; td.base[5] = 86016;
  transpose_all<<<(86016 + 255) / 256, 256, 0, stream>>>(td, wt_all, flag);

  int gb = (N + 63) / 64;          // 782
  int ngroups = (N + 15) / 16;     // 3125
  gemm_l1<<<gb, 256, 0, stream>>>(x, c, me_x, me_c, w1e_t, w1c_t, N, tbuf, flag);
  agg1_half<<<2048, 256, 0, stream>>>(tbuf, rowptr, colarr,
      e1e, e1c, b1e, b1c, ubuf, N, ngroups, flag);
  gemm_l2<<<gb, 256, 0, stream>>>(ubuf, w2e_t, w2c_t, N, tbuf);
  agg2_half<<<2048, 256, 0, stream>>>(tbuf, rowptr, colarr,
      e2e, e2c, b2e, b2c, wm_t, (float*)d_out, N, ngroups, flag);
  head_epi<<<(N * 8 + 255) / 256, 256, 0, stream>>>((float*)d_out, bm, N * 8, flag);
  mlp_kernel<<<Cn, 128, 0, stream>>>((const float*)d_out, cidx,
      Wp1, bp1, Wp2, bp2, (float*)d_out + (size_t)N * 8, flag);
}